// Round 1
// baseline (86.688 us; speedup 1.0000x reference)
//
#include <hip/hip_runtime.h>
#include <hip/hip_bf16.h>
#include <math.h>

#define NDIM 4096
#define MDIM 4096
#define LDIM 512
#define KDIM 1024

typedef short bf16x8 __attribute__((ext_vector_type(8)));
typedef float f32x4 __attribute__((ext_vector_type(4)));

#define GLOBAL_AS __attribute__((address_space(1)))
#define LDS_AS __attribute__((address_space(3)))

__device__ __align__(16) __hip_bfloat16 g_A[(size_t)NDIM * KDIM];
__device__ __align__(16) __hip_bfloat16 g_B[(size_t)MDIM * KDIM];

__device__ inline void gload_lds16(void* lds, const void* g) {
  __builtin_amdgcn_global_load_lds((const GLOBAL_AS void*)g, (LDS_AS void*)lds, 16, 0, 0);
}

// ---------------------------------------------------------------------------
// Phase kernel: A[n][l] = s*w_l*cos(px), A[n][l+512] = s*w_l*sin(px)
//               B[m][l] = cos(py),       B[m][l+512] = sin(py)
// where s = |var| / sum_l w_l, w_l = exp(-0.5*lam_l).
// Grid: 8192 blocks (0..4095 -> A rows, 4096..8191 -> B rows), 512 threads.
// ---------------------------------------------------------------------------
__global__ __launch_bounds__(512) void phase_kernel(const float* __restrict__ x,
                                                    const float* __restrict__ y,
                                                    const float* __restrict__ freqs,
                                                    const float* __restrict__ lam,
                                                    const float* __restrict__ var) {
  int l = threadIdx.x;          // 0..511  (eigenvalue index)
  int r = blockIdx.x;           // 0..8191 (row index across A then B)
  float w = expf(-0.5f * lam[l]);

  // block-wide sum of w (redundant per block; trivial cost)
  float v = w;
  #pragma unroll
  for (int off = 32; off > 0; off >>= 1) v += __shfl_down(v, off, 64);
  __shared__ float red[8];
  __shared__ float s_scale;
  int lane = l & 63, wv = l >> 6;
  if (lane == 0) red[wv] = v;
  __syncthreads();
  if (l == 0) {
    float t = 0.f;
    #pragma unroll
    for (int i = 0; i < 8; ++i) t += red[i];
    s_scale = fabsf(var[0]) / t;
  }
  __syncthreads();

  float f0 = freqs[l * 3 + 0], f1 = freqs[l * 3 + 1], f2 = freqs[l * 3 + 2];
  bool isA = (r < NDIM);
  int rr = isA ? r : (r - NDIM);
  const float* p = isA ? (x + (size_t)rr * 3) : (y + (size_t)rr * 3);
  float px = p[0] * f0 + p[1] * f1 + p[2] * f2;
  float sn, cs;
  sincosf(px, &sn, &cs);
  float wgt = isA ? (w * s_scale) : 1.0f;
  __hip_bfloat16* dst = (isA ? g_A : g_B) + (size_t)rr * KDIM;
  dst[l]        = __float2bfloat16(wgt * cs);
  dst[l + LDIM] = __float2bfloat16(wgt * sn);
}

// ---------------------------------------------------------------------------
// GEMM: C[4096][4096] f32 = A[4096][1024]bf16 @ B[4096][1024]bf16 ^T
// m97 structure: 128x128 tile, BK=64, 4 waves (2x2), 4x4 frags of 16x16x32,
// global_load_lds width 16, single-buffer 2-barrier K loop, XCD swizzle.
// ---------------------------------------------------------------------------
__global__ __launch_bounds__(256) void gemm_kernel(float* __restrict__ C) {
  __shared__ __align__(16) short As[128][64];
  __shared__ __align__(16) short Bs[128][64];

  int bid = blockIdx.x;                       // 0..1023
  // XCD-aware swizzle (1024 % 8 == 0 -> simple form is bijective)
  int swz = (bid & 7) * 128 + (bid >> 3);
  int brow = (swz >> 5) * 128;
  int bcol = (swz & 31) * 128;

  int tid  = threadIdx.x;
  int lane = tid & 63;
  int wv   = tid >> 6;
  int wr   = (wv >> 1) * 64;                  // wave row offset in tile
  int wc   = (wv & 1) * 64;                   // wave col offset in tile

  f32x4 acc[4][4] = {};

  const short* Ab = (const short*)g_A;
  const short* Bb = (const short*)g_B;

  int lrow = lane >> 3;                       // 0..7
  int lcol = (lane & 7) * 8;                  // bf16 element col, 0..56

  for (int kt = 0; kt < KDIM; kt += 64) {
    // ---- stage A,B tiles: 4 issues each, 16B/lane, linear LDS dest ----
    #pragma unroll
    for (int i = 0; i < 4; ++i) {
      int row = i * 32 + wv * 8 + lrow;       // 0..127
      const short* ga = Ab + (size_t)(brow + row) * KDIM + kt + lcol;
      const short* gb = Bb + (size_t)(bcol + row) * KDIM + kt + lcol;
      gload_lds16(&As[i * 32 + wv * 8][0], ga);
      gload_lds16(&Bs[i * 32 + wv * 8][0], gb);
    }
    __syncthreads();

    // ---- compute: 2 k-steps of 32, 16 MFMAs each ----
    #pragma unroll
    for (int kk = 0; kk < 2; ++kk) {
      bf16x8 af[4], bfr[4];
      int col = kk * 32 + (lane >> 4) * 8;
      int fr  = lane & 15;
      #pragma unroll
      for (int m = 0; m < 4; ++m)
        af[m] = *(const bf16x8*)&As[wr + m * 16 + fr][col];
      #pragma unroll
      for (int n = 0; n < 4; ++n)
        bfr[n] = *(const bf16x8*)&Bs[wc + n * 16 + fr][col];
      #pragma unroll
      for (int m = 0; m < 4; ++m)
        #pragma unroll
        for (int n = 0; n < 4; ++n)
          acc[m][n] = __builtin_amdgcn_mfma_f32_16x16x32_bf16(af[m], bfr[n], acc[m][n], 0, 0, 0);
    }
    __syncthreads();
  }

  // ---- epilogue: C/D layout col=lane&15, row=(lane>>4)*4+j (m89/m91) ----
  int crow0 = brow + wr + (lane >> 4) * 4;
  int ccol0 = bcol + wc + (lane & 15);
  #pragma unroll
  for (int m = 0; m < 4; ++m)
    #pragma unroll
    for (int n = 0; n < 4; ++n)
      #pragma unroll
      for (int j = 0; j < 4; ++j)
        C[(size_t)(crow0 + m * 16 + j) * MDIM + (ccol0 + n * 16)] = acc[m][n][j];
}

extern "C" void kernel_launch(void* const* d_in, const int* in_sizes, int n_in,
                              void* d_out, int out_size, void* d_ws, size_t ws_size,
                              hipStream_t stream) {
  const float* x     = (const float*)d_in[0];
  const float* y     = (const float*)d_in[1];
  const float* freqs = (const float*)d_in[2];
  const float* lam   = (const float*)d_in[3];
  const float* var   = (const float*)d_in[4];
  float* out = (float*)d_out;

  hipLaunchKernelGGL(phase_kernel, dim3(NDIM + MDIM), dim3(512), 0, stream,
                     x, y, freqs, lam, var);
  hipLaunchKernelGGL(gemm_kernel, dim3((NDIM / 128) * (MDIM / 128)), dim3(256), 0, stream,
                     out);
}

// Round 2
// 71.769 us; speedup vs baseline: 1.2079x; 1.2079x over previous
//
#include <hip/hip_runtime.h>
#include <hip/hip_bf16.h>
#include <math.h>

#define NDIM 4096
#define MDIM 4096
#define LDIM 512
#define KDIM 1024
#define NT   16     // K-tiles of BK=64

typedef short bf16x8 __attribute__((ext_vector_type(8)));
typedef float f32x4 __attribute__((ext_vector_type(4)));

#define GLOBAL_AS __attribute__((address_space(1)))
#define LDS_AS __attribute__((address_space(3)))

__device__ __align__(16) __hip_bfloat16 g_A[(size_t)NDIM * KDIM];
__device__ __align__(16) __hip_bfloat16 g_B[(size_t)MDIM * KDIM];

__device__ __forceinline__ void gload_lds16(void* lds, const void* g) {
  __builtin_amdgcn_global_load_lds((const GLOBAL_AS void*)g, (LDS_AS void*)lds, 16, 0, 0);
}

// ---------------------------------------------------------------------------
// Phase kernel: A[n][l] = s*w_l*cos(px), A[n][l+512] = s*w_l*sin(px)
//               B[m][l] = cos(py),       B[m][l+512] = sin(py)
// ---------------------------------------------------------------------------
__global__ __launch_bounds__(512) void phase_kernel(const float* __restrict__ x,
                                                    const float* __restrict__ y,
                                                    const float* __restrict__ freqs,
                                                    const float* __restrict__ lam,
                                                    const float* __restrict__ var) {
  int l = threadIdx.x;          // 0..511
  int r = blockIdx.x;           // 0..8191
  float w = expf(-0.5f * lam[l]);

  float v = w;
  #pragma unroll
  for (int off = 32; off > 0; off >>= 1) v += __shfl_down(v, off, 64);
  __shared__ float red[8];
  __shared__ float s_scale;
  int lane = l & 63, wv = l >> 6;
  if (lane == 0) red[wv] = v;
  __syncthreads();
  if (l == 0) {
    float t = 0.f;
    #pragma unroll
    for (int i = 0; i < 8; ++i) t += red[i];
    s_scale = fabsf(var[0]) / t;
  }
  __syncthreads();

  float f0 = freqs[l * 3 + 0], f1 = freqs[l * 3 + 1], f2 = freqs[l * 3 + 2];
  bool isA = (r < NDIM);
  int rr = isA ? r : (r - NDIM);
  const float* p = isA ? (x + (size_t)rr * 3) : (y + (size_t)rr * 3);
  float px = p[0] * f0 + p[1] * f1 + p[2] * f2;
  float sn, cs;
  __sincosf(px, &sn, &cs);
  float wgt = isA ? (w * s_scale) : 1.0f;
  __hip_bfloat16* dst = (isA ? g_A : g_B) + (size_t)rr * KDIM;
  dst[l]        = __float2bfloat16(wgt * cs);
  dst[l + LDIM] = __float2bfloat16(wgt * sn);
}

// ---------------------------------------------------------------------------
// GEMM: C[4096][4096] f32 = A @ B^T, bf16 inputs, K=1024.
// 256x256 tile, BK=64, 8 waves (2Mx4N), 8-phase-per-2-K-tiles schedule with
// K-split half-tiles (256x32 per operand half), counted vmcnt(4) waits,
// swizzled LDS (byte ^= ((row>>1)&3)<<4 within 64B rows), setprio around MFMA.
// ---------------------------------------------------------------------------
__global__ __launch_bounds__(512) void gemm_kernel(float* __restrict__ C) {
  // [buf][kk][row*32 + col] bf16; each half-block 16 KB, contiguous.
  __shared__ __align__(16) short Al[2][2][256 * 32];
  __shared__ __align__(16) short Bl[2][2][256 * 32];

  int bid = blockIdx.x;                 // 0..255
  int swz = (bid & 7) * 32 + (bid >> 3);  // XCD swizzle (256 % 8 == 0)
  int brow = (swz >> 4) * 256;
  int bcol = (swz & 15) * 256;

  int tid  = threadIdx.x;
  int lane = tid & 63;
  int wid  = tid >> 6;                  // 0..7
  int wm   = wid >> 2;                  // 0..1 -> rows wm*128..+127
  int wn   = wid & 3;                   // 0..3 -> cols wn*64..+63

  // ---- ds_read offsets (swizzled). XOR term depends only on fr bits 1-2. ----
  int fr   = lane & 15;
  int cs_  = ((lane >> 4) * 16) ^ (((fr >> 1) & 3) << 4);
  int offA[8], offB[4];
  #pragma unroll
  for (int m = 0; m < 8; ++m) offA[m] = (wm * 128 + m * 16 + fr) * 64 + cs_;
  #pragma unroll
  for (int n = 0; n < 4; ++n) offB[n] = (wn * 64 + n * 16 + fr) * 64 + cs_;

  // ---- staging per-thread constants (pre-swizzled global source) ----
  int srow = tid >> 2;                                        // 0..127
  int scb  = ((tid & 3) * 16) ^ (((srow >> 1) & 3) << 4);     // byte in 64B row
  const short* gA = (const short*)g_A + (size_t)(brow + srow) * KDIM + scb / 2;
  const short* gB = (const short*)g_B + (size_t)(bcol + srow) * KDIM + scb / 2;

  f32x4 acc[8][4] = {};

  // Stage one half-tile (256 rows x 32 cols): 2 issues, rows 0-127 / 128-255.
#define STAGE(ARR, GPTR, T1, KK)                                             \
  {                                                                          \
    char* d_ = (char*)(&ARR[(T1) & 1][(KK)][0]) + wid * 1024;                \
    const short* s_ = (GPTR) + (T1) * 64 + (KK) * 32;                        \
    gload_lds16(d_, s_);                                                     \
    gload_lds16(d_ + 8192, s_ + (size_t)128 * KDIM);                         \
  }

#define VMCNT(N) asm volatile("s_waitcnt vmcnt(" #N ")" ::: "memory")

#define MFMA4(G, I, AF)                                                               \
  acc[(G)*4+(I)][0] = __builtin_amdgcn_mfma_f32_16x16x32_bf16(AF, bq0, acc[(G)*4+(I)][0], 0, 0, 0); \
  acc[(G)*4+(I)][1] = __builtin_amdgcn_mfma_f32_16x16x32_bf16(AF, bq1, acc[(G)*4+(I)][1], 0, 0, 0); \
  acc[(G)*4+(I)][2] = __builtin_amdgcn_mfma_f32_16x16x32_bf16(AF, bq2, acc[(G)*4+(I)][2], 0, 0, 0); \
  acc[(G)*4+(I)][3] = __builtin_amdgcn_mfma_f32_16x16x32_bf16(AF, bq3, acc[(G)*4+(I)][3], 0, 0, 0);

  // Phase: ds_read 4 A-frags + 4 B-frags -> stage(next) -> barrier ->
  //        setprio(1) 16 MFMA setprio(0) -> guard -> barrier.
#define PHASE(BUF, KK, G, GUARD, ...)                                        \
  {                                                                          \
    const char* Ab = (const char*)(&Al[(BUF)][(KK)][0]);                     \
    const char* Bb = (const char*)(&Bl[(BUF)][(KK)][0]);                     \
    bf16x8 aq0 = *(const bf16x8*)(Ab + offA[(G)*4 + 0]);                     \
    bf16x8 aq1 = *(const bf16x8*)(Ab + offA[(G)*4 + 1]);                     \
    bf16x8 aq2 = *(const bf16x8*)(Ab + offA[(G)*4 + 2]);                     \
    bf16x8 aq3 = *(const bf16x8*)(Ab + offA[(G)*4 + 3]);                     \
    bf16x8 bq0 = *(const bf16x8*)(Bb + offB[0]);                             \
    bf16x8 bq1 = *(const bf16x8*)(Bb + offB[1]);                             \
    bf16x8 bq2 = *(const bf16x8*)(Bb + offB[2]);                             \
    bf16x8 bq3 = *(const bf16x8*)(Bb + offB[3]);                             \
    __VA_ARGS__;                                                             \
    __builtin_amdgcn_s_barrier();                                            \
    __builtin_amdgcn_s_setprio(1);                                           \
    MFMA4(G, 0, aq0)                                                         \
    MFMA4(G, 1, aq1)                                                         \
    MFMA4(G, 2, aq2)                                                         \
    MFMA4(G, 3, aq3)                                                         \
    __builtin_amdgcn_s_setprio(0);                                           \
    GUARD;                                                                   \
    __builtin_amdgcn_s_barrier();                                            \
  }

  // ---- prologue: stage tile 0 (order A.k0, B.k0, A.k1, B.k1 = 8 loads) ----
  STAGE(Al, gA, 0, 0);
  STAGE(Bl, gB, 0, 0);
  STAGE(Al, gA, 0, 1);
  STAGE(Bl, gB, 0, 1);
  VMCNT(4);                      // A.k0(0), B.k0(0) landed; k1 halves in flight
  __builtin_amdgcn_s_barrier();

  // ---- main loop: per tile 4 phases; stages of t+1 spread across them ----
  for (int t = 0; t < NT; ++t) {
    const int buf = t & 1;
    const bool nl = (t + 1 < NT);
    // ph1: kk=0, m 0-3; stage A.k0(t+1)
    PHASE(buf, 0, 0, , if (nl) STAGE(Al, gA, t + 1, 0));
    // ph2: kk=0, m 4-7; stage B.k0(t+1); guard k1 halves of THIS tile
    PHASE(buf, 0, 1, if (nl) { VMCNT(4); } else { VMCNT(0); },
          if (nl) STAGE(Bl, gB, t + 1, 0));
    // ph3: kk=1, m 0-3; stage A.k1(t+1)
    PHASE(buf, 1, 0, , if (nl) STAGE(Al, gA, t + 1, 1));
    // ph4: kk=1, m 4-7; stage B.k1(t+1); guard k0 halves of NEXT tile
    PHASE(buf, 1, 1, if (nl) { VMCNT(4); },
          if (nl) STAGE(Bl, gB, t + 1, 1));
  }

  // ---- epilogue: C/D layout col=lane&15, row=(lane>>4)*4+j ----
  int crow = brow + wm * 128 + (lane >> 4) * 4;
  int ccol = bcol + wn * 64 + (lane & 15);
  #pragma unroll
  for (int mi = 0; mi < 8; ++mi)
    #pragma unroll
    for (int n = 0; n < 4; ++n)
      #pragma unroll
      for (int j = 0; j < 4; ++j)
        C[(size_t)(crow + mi * 16 + j) * MDIM + (ccol + n * 16)] = acc[mi][n][j];
}

extern "C" void kernel_launch(void* const* d_in, const int* in_sizes, int n_in,
                              void* d_out, int out_size, void* d_ws, size_t ws_size,
                              hipStream_t stream) {
  const float* x     = (const float*)d_in[0];
  const float* y     = (const float*)d_in[1];
  const float* freqs = (const float*)d_in[2];
  const float* lam   = (const float*)d_in[3];
  const float* var   = (const float*)d_in[4];
  float* out = (float*)d_out;

  hipLaunchKernelGGL(phase_kernel, dim3(NDIM + MDIM), dim3(512), 0, stream,
                     x, y, freqs, lam, var);
  hipLaunchKernelGGL(gemm_kernel, dim3((NDIM / 256) * (MDIM / 256)), dim3(512), 0, stream,
                     out);
}

// Round 3
// 71.448 us; speedup vs baseline: 1.2133x; 1.0045x over previous
//
#include <hip/hip_runtime.h>
#include <hip/hip_bf16.h>
#include <math.h>

#define NDIM 4096
#define MDIM 4096
#define LDIM 512
#define KDIM 1024
#define NT   16     // K-tiles of BK=64

typedef short bf16x8 __attribute__((ext_vector_type(8)));
typedef float f32x4 __attribute__((ext_vector_type(4)));

#define GLOBAL_AS __attribute__((address_space(1)))
#define LDS_AS __attribute__((address_space(3)))

__device__ __align__(16) __hip_bfloat16 g_A[(size_t)NDIM * KDIM];
__device__ __align__(16) __hip_bfloat16 g_B[(size_t)MDIM * KDIM];

__device__ __forceinline__ void gload_lds16(void* lds, const void* g) {
  __builtin_amdgcn_global_load_lds((const GLOBAL_AS void*)g, (LDS_AS void*)lds, 16, 0, 0);
}

// ---------------------------------------------------------------------------
// Phase kernel: A[n][l] = s*w_l*cos(px), A[n][l+512] = s*w_l*sin(px)
//               B[m][l] = cos(py),       B[m][l+512] = sin(py)
// ---------------------------------------------------------------------------
__global__ __launch_bounds__(512) void phase_kernel(const float* __restrict__ x,
                                                    const float* __restrict__ y,
                                                    const float* __restrict__ freqs,
                                                    const float* __restrict__ lam,
                                                    const float* __restrict__ var) {
  int l = threadIdx.x;          // 0..511
  int r = blockIdx.x;           // 0..8191
  float w = expf(-0.5f * lam[l]);

  float v = w;
  #pragma unroll
  for (int off = 32; off > 0; off >>= 1) v += __shfl_down(v, off, 64);
  __shared__ float red[8];
  __shared__ float s_scale;
  int lane = l & 63, wv = l >> 6;
  if (lane == 0) red[wv] = v;
  __syncthreads();
  if (l == 0) {
    float t = 0.f;
    #pragma unroll
    for (int i = 0; i < 8; ++i) t += red[i];
    s_scale = fabsf(var[0]) / t;
  }
  __syncthreads();

  float f0 = freqs[l * 3 + 0], f1 = freqs[l * 3 + 1], f2 = freqs[l * 3 + 2];
  bool isA = (r < NDIM);
  int rr = isA ? r : (r - NDIM);
  const float* p = isA ? (x + (size_t)rr * 3) : (y + (size_t)rr * 3);
  float px = p[0] * f0 + p[1] * f1 + p[2] * f2;
  float sn, cs;
  __sincosf(px, &sn, &cs);
  float wgt = isA ? (w * s_scale) : 1.0f;
  __hip_bfloat16* dst = (isA ? g_A : g_B) + (size_t)rr * KDIM;
  dst[l]        = __float2bfloat16(wgt * cs);
  dst[l + LDIM] = __float2bfloat16(wgt * sn);
}

// ---------------------------------------------------------------------------
// GEMM: C[4096][4096] f32 = A @ B^T, bf16 inputs, K=1024.
// 256x256 tile, BK=64, 8 waves (2Mx4N), 4 phases/K-tile, B-frag reuse across
// the two m-half phases (24 ds_read_b128/tile/wave, template-equivalent),
// counted vmcnt(4), swizzled LDS, lgkmcnt(0)+sched_barrier pinned MFMA
// clusters, setprio(1) around MFMA.
// ---------------------------------------------------------------------------
__global__ __launch_bounds__(512) void gemm_kernel(float* __restrict__ C) {
  // [buf][kk][row*32 + col] bf16; each half-block 16 KB, contiguous.
  __shared__ __align__(16) short Al[2][2][256 * 32];
  __shared__ __align__(16) short Bl[2][2][256 * 32];

  int bid = blockIdx.x;                 // 0..255
  int swz = (bid & 7) * 32 + (bid >> 3);  // XCD swizzle (256 % 8 == 0)
  int brow = (swz >> 4) * 256;
  int bcol = (swz & 15) * 256;

  int tid  = threadIdx.x;
  int lane = tid & 63;
  int wid  = tid >> 6;                  // 0..7
  int wm   = wid >> 2;                  // 0..1 -> rows wm*128..+127
  int wn   = wid & 3;                   // 0..3 -> cols wn*64..+63

  // ---- ds_read offsets (swizzled). XOR term depends only on fr bits 1-2. ----
  int fr   = lane & 15;
  int cs_  = ((lane >> 4) * 16) ^ (((fr >> 1) & 3) << 4);
  int offA[8], offB[4];
  #pragma unroll
  for (int m = 0; m < 8; ++m) offA[m] = (wm * 128 + m * 16 + fr) * 64 + cs_;
  #pragma unroll
  for (int n = 0; n < 4; ++n) offB[n] = (wn * 64 + n * 16 + fr) * 64 + cs_;

  // ---- staging per-thread constants (pre-swizzled global source) ----
  int srow = tid >> 2;                                        // 0..127
  int scb  = ((tid & 3) * 16) ^ (((srow >> 1) & 3) << 4);     // byte in 64B row
  const short* gA = (const short*)g_A + (size_t)(brow + srow) * KDIM + scb / 2;
  const short* gB = (const short*)g_B + (size_t)(bcol + srow) * KDIM + scb / 2;

  f32x4 acc[8][4] = {};

  // Stage one half-tile (256 rows x 32 cols): 2 issues, rows 0-127 / 128-255.
#define STAGE(ARR, GPTR, T1, KK)                                             \
  {                                                                          \
    char* d_ = (char*)(&ARR[(T1) & 1][(KK)][0]) + wid * 1024;                \
    const short* s_ = (GPTR) + (T1) * 64 + (KK) * 32;                        \
    gload_lds16(d_, s_);                                                     \
    gload_lds16(d_ + 8192, s_ + (size_t)128 * KDIM);                         \
  }

#define VMCNT(N) asm volatile("s_waitcnt vmcnt(" #N ")" ::: "memory")
#define LGKM0   asm volatile("s_waitcnt lgkmcnt(0)" ::: "memory")
#define SCHED0  __builtin_amdgcn_sched_barrier(0)

#define MFMA4(G, I, AF)                                                               \
  acc[(G)*4+(I)][0] = __builtin_amdgcn_mfma_f32_16x16x32_bf16(AF, bq0, acc[(G)*4+(I)][0], 0, 0, 0); \
  acc[(G)*4+(I)][1] = __builtin_amdgcn_mfma_f32_16x16x32_bf16(AF, bq1, acc[(G)*4+(I)][1], 0, 0, 0); \
  acc[(G)*4+(I)][2] = __builtin_amdgcn_mfma_f32_16x16x32_bf16(AF, bq2, acc[(G)*4+(I)][2], 0, 0, 0); \
  acc[(G)*4+(I)][3] = __builtin_amdgcn_mfma_f32_16x16x32_bf16(AF, bq3, acc[(G)*4+(I)][3], 0, 0, 0);

  // ---- prologue: stage tile 0 (order A.k0, B.k0, A.k1, B.k1 = 8 loads) ----
  STAGE(Al, gA, 0, 0);
  STAGE(Bl, gB, 0, 0);
  STAGE(Al, gA, 0, 1);
  STAGE(Bl, gB, 0, 1);
  VMCNT(4);                      // A.k0(0), B.k0(0) landed; k1 halves in flight
  __builtin_amdgcn_s_barrier();

  // ---- main loop: per tile 4 phases; stages of t+1 spread across them ----
  for (int t = 0; t < NT; ++t) {
    const int buf = t & 1;
    const bool nl = (t + 1 < NT);
    const char* Ab0 = (const char*)(&Al[buf][0][0]);
    const char* Bb0 = (const char*)(&Bl[buf][0][0]);
    const char* Ab1 = (const char*)(&Al[buf][1][0]);
    const char* Bb1 = (const char*)(&Bl[buf][1][0]);
    bf16x8 aq0, aq1, aq2, aq3, bq0, bq1, bq2, bq3;

    // ---- ph1: kk0, m0-3; read A0-3 + B0-3; stage A.k0(t+1) ----
    aq0 = *(const bf16x8*)(Ab0 + offA[0]);
    aq1 = *(const bf16x8*)(Ab0 + offA[1]);
    aq2 = *(const bf16x8*)(Ab0 + offA[2]);
    aq3 = *(const bf16x8*)(Ab0 + offA[3]);
    bq0 = *(const bf16x8*)(Bb0 + offB[0]);
    bq1 = *(const bf16x8*)(Bb0 + offB[1]);
    bq2 = *(const bf16x8*)(Bb0 + offB[2]);
    bq3 = *(const bf16x8*)(Bb0 + offB[3]);
    if (nl) STAGE(Al, gA, t + 1, 0);
    __builtin_amdgcn_s_barrier();
    LGKM0; SCHED0;
    __builtin_amdgcn_s_setprio(1);
    MFMA4(0, 0, aq0) MFMA4(0, 1, aq1) MFMA4(0, 2, aq2) MFMA4(0, 3, aq3)
    __builtin_amdgcn_s_setprio(0);
    __builtin_amdgcn_s_barrier();

    // ---- ph2: kk0, m4-7; read A4-7 (reuse bq); stage B.k0(t+1) ----
    aq0 = *(const bf16x8*)(Ab0 + offA[4]);
    aq1 = *(const bf16x8*)(Ab0 + offA[5]);
    aq2 = *(const bf16x8*)(Ab0 + offA[6]);
    aq3 = *(const bf16x8*)(Ab0 + offA[7]);
    if (nl) STAGE(Bl, gB, t + 1, 0);
    __builtin_amdgcn_s_barrier();
    LGKM0; SCHED0;
    __builtin_amdgcn_s_setprio(1);
    MFMA4(1, 0, aq0) MFMA4(1, 1, aq1) MFMA4(1, 2, aq2) MFMA4(1, 3, aq3)
    __builtin_amdgcn_s_setprio(0);
    if (nl) { VMCNT(4); } else { VMCNT(0); }   // this-tile k1 halves landed
    __builtin_amdgcn_s_barrier();

    // ---- ph3: kk1, m0-3; read A0-3 + B0-3; stage A.k1(t+1) ----
    aq0 = *(const bf16x8*)(Ab1 + offA[0]);
    aq1 = *(const bf16x8*)(Ab1 + offA[1]);
    aq2 = *(const bf16x8*)(Ab1 + offA[2]);
    aq3 = *(const bf16x8*)(Ab1 + offA[3]);
    bq0 = *(const bf16x8*)(Bb1 + offB[0]);
    bq1 = *(const bf16x8*)(Bb1 + offB[1]);
    bq2 = *(const bf16x8*)(Bb1 + offB[2]);
    bq3 = *(const bf16x8*)(Bb1 + offB[3]);
    if (nl) STAGE(Al, gA, t + 1, 1);
    __builtin_amdgcn_s_barrier();
    LGKM0; SCHED0;
    __builtin_amdgcn_s_setprio(1);
    MFMA4(0, 0, aq0) MFMA4(0, 1, aq1) MFMA4(0, 2, aq2) MFMA4(0, 3, aq3)
    __builtin_amdgcn_s_setprio(0);
    __builtin_amdgcn_s_barrier();

    // ---- ph4: kk1, m4-7; read A4-7 (reuse bq); stage B.k1(t+1) ----
    aq0 = *(const bf16x8*)(Ab1 + offA[4]);
    aq1 = *(const bf16x8*)(Ab1 + offA[5]);
    aq2 = *(const bf16x8*)(Ab1 + offA[6]);
    aq3 = *(const bf16x8*)(Ab1 + offA[7]);
    if (nl) STAGE(Bl, gB, t + 1, 1);
    __builtin_amdgcn_s_barrier();
    LGKM0; SCHED0;
    __builtin_amdgcn_s_setprio(1);
    MFMA4(1, 0, aq0) MFMA4(1, 1, aq1) MFMA4(1, 2, aq2) MFMA4(1, 3, aq3)
    __builtin_amdgcn_s_setprio(0);
    if (nl) { VMCNT(4); }                      // next-tile k0 halves landed
    __builtin_amdgcn_s_barrier();
  }

  // ---- epilogue: C/D layout col=lane&15, row=(lane>>4)*4+j ----
  int crow = brow + wm * 128 + (lane >> 4) * 4;
  int ccol = bcol + wn * 64 + (lane & 15);
  #pragma unroll
  for (int mi = 0; mi < 8; ++mi)
    #pragma unroll
    for (int n = 0; n < 4; ++n)
      #pragma unroll
      for (int j = 0; j < 4; ++j)
        C[(size_t)(crow + mi * 16 + j) * MDIM + (ccol + n * 16)] = acc[mi][n][j];
}

extern "C" void kernel_launch(void* const* d_in, const int* in_sizes, int n_in,
                              void* d_out, int out_size, void* d_ws, size_t ws_size,
                              hipStream_t stream) {
  const float* x     = (const float*)d_in[0];
  const float* y     = (const float*)d_in[1];
  const float* freqs = (const float*)d_in[2];
  const float* lam   = (const float*)d_in[3];
  const float* var   = (const float*)d_in[4];
  float* out = (float*)d_out;

  hipLaunchKernelGGL(phase_kernel, dim3(NDIM + MDIM), dim3(512), 0, stream,
                     x, y, freqs, lam, var);
  hipLaunchKernelGGL(gemm_kernel, dim3((NDIM / 256) * (MDIM / 256)), dim3(512), 0, stream,
                     out);
}

// Round 4
// 62.641 us; speedup vs baseline: 1.3839x; 1.1406x over previous
//
#include <hip/hip_runtime.h>
#include <hip/hip_bf16.h>
#include <math.h>

#define NDIM 4096
#define MDIM 4096
#define LDIM 512
#define KDIM 1024
#define NT   16     // K-tiles of BK=64

typedef short bf16x8 __attribute__((ext_vector_type(8)));
typedef float f32x4 __attribute__((ext_vector_type(4)));

#define GLOBAL_AS __attribute__((address_space(1)))
#define LDS_AS __attribute__((address_space(3)))

__device__ __align__(16) __hip_bfloat16 g_A[(size_t)NDIM * KDIM];
__device__ __align__(16) __hip_bfloat16 g_B[(size_t)MDIM * KDIM];

__device__ __forceinline__ void gload_lds16(void* lds, const void* g) {
  __builtin_amdgcn_global_load_lds((const GLOBAL_AS void*)g, (LDS_AS void*)lds, 16, 0, 0);
}

// ---------------------------------------------------------------------------
// scale_kernel: ws[0] = |var| / sum_l exp(-0.5*lam_l)   (1 block, 512 thr)
// ---------------------------------------------------------------------------
__global__ __launch_bounds__(512) void scale_kernel(const float* __restrict__ lam,
                                                    const float* __restrict__ var,
                                                    float* __restrict__ ws) {
  int l = threadIdx.x;
  float v = expf(-0.5f * lam[l]);
  #pragma unroll
  for (int off = 32; off > 0; off >>= 1) v += __shfl_down(v, off, 64);
  __shared__ float red[8];
  if ((l & 63) == 0) red[l >> 6] = v;
  __syncthreads();
  if (l == 0) {
    float t = 0.f;
    #pragma unroll
    for (int i = 0; i < 8; ++i) t += red[i];
    ws[0] = fabsf(var[0]) / t;
  }
}

// ---------------------------------------------------------------------------
// Phase kernel (no reduction): A[n][l] = s*w_l*cos(px), A[n][l+512] = s*w_l*sin
//                              B[m][l] = cos(py),       B[m][l+512] = sin(py)
// ---------------------------------------------------------------------------
__global__ __launch_bounds__(512) void phase_kernel(const float* __restrict__ x,
                                                    const float* __restrict__ y,
                                                    const float* __restrict__ freqs,
                                                    const float* __restrict__ lam,
                                                    const float* __restrict__ ws) {
  int l = threadIdx.x;          // 0..511
  int r = blockIdx.x;           // 0..8191
  float s = ws[0];
  float w = expf(-0.5f * lam[l]);
  float f0 = freqs[l * 3 + 0], f1 = freqs[l * 3 + 1], f2 = freqs[l * 3 + 2];
  bool isA = (r < NDIM);
  int rr = isA ? r : (r - NDIM);
  const float* p = isA ? (x + (size_t)rr * 3) : (y + (size_t)rr * 3);
  float px = p[0] * f0 + p[1] * f1 + p[2] * f2;
  float sn, cs;
  __sincosf(px, &sn, &cs);
  float wgt = isA ? (w * s) : 1.0f;
  __hip_bfloat16* dst = (isA ? g_A : g_B) + (size_t)rr * KDIM;
  dst[l]        = __float2bfloat16(wgt * cs);
  dst[l + LDIM] = __float2bfloat16(wgt * sn);
}

// ---------------------------------------------------------------------------
// GEMM: C[4096][4096] f32 = A @ B^T, bf16, K=1024.
// 256x256 tile, BK=64, 8 waves (2Mx4N). 2 phases/K-tile, 32 MFMA/phase.
// A-fragments double-buffered in regs, read ONE PHASE AHEAD (latency hidden
// under previous MFMA); B read at phase top with lgkmcnt(8) partial wait.
// Counted vmcnt(4) (never 0 mid-loop), 1 barrier per phase (4/tile).
// ---------------------------------------------------------------------------
__global__ __launch_bounds__(512, 2) void gemm_kernel(float* __restrict__ C) {
  // [buf][kk][row*32 + col] bf16; each half-block 16 KB, contiguous.
  __shared__ __align__(16) short Al[2][2][256 * 32];
  __shared__ __align__(16) short Bl[2][2][256 * 32];

  int bid = blockIdx.x;                   // 0..255
  int swz = (bid & 7) * 32 + (bid >> 3);  // XCD swizzle (256 % 8 == 0)
  int brow = (swz >> 4) * 256;
  int bcol = (swz & 15) * 256;

  int tid  = threadIdx.x;
  int lane = tid & 63;
  int wid  = tid >> 6;                    // 0..7
  int wm   = wid >> 2;                    // 0..1 -> rows wm*128..+127
  int wn   = wid & 3;                     // 0..3 -> cols wn*64..+63

  // ds_read offsets (swizzled: byte ^= ((row>>1)&3)<<4 within 64B rows)
  int fr   = lane & 15;
  int cs_  = ((lane >> 4) * 16) ^ (((fr >> 1) & 3) << 4);
  int offA[8], offB[4];
  #pragma unroll
  for (int m = 0; m < 8; ++m) offA[m] = (wm * 128 + m * 16 + fr) * 64 + cs_;
  #pragma unroll
  for (int n = 0; n < 4; ++n) offB[n] = (wn * 64 + n * 16 + fr) * 64 + cs_;

  // staging per-thread constants (pre-swizzled global source)
  int srow = tid >> 2;                                        // 0..127
  int scb  = ((tid & 3) * 16) ^ (((srow >> 1) & 3) << 4);     // byte in 64B row
  const short* gA = (const short*)g_A + (size_t)(brow + srow) * KDIM + scb / 2;
  const short* gB = (const short*)g_B + (size_t)(bcol + srow) * KDIM + scb / 2;

  f32x4 acc[8][4] = {};
  bf16x8 s0_0, s0_1, s0_2, s0_3, s0_4, s0_5, s0_6, s0_7;   // A set0 (kk0)
  bf16x8 s1_0, s1_1, s1_2, s1_3, s1_4, s1_5, s1_6, s1_7;   // A set1 (kk1)
  bf16x8 bq0, bq1, bq2, bq3;

#define STAGE(ARR, GPTR, T1, KK)                                             \
  {                                                                          \
    char* d_ = (char*)(&ARR[(T1) & 1][(KK)][0]) + wid * 1024;                \
    const short* s_ = (GPTR) + (T1) * 64 + (KK) * 32;                        \
    gload_lds16(d_, s_);                                                     \
    gload_lds16(d_ + 8192, s_ + (size_t)128 * KDIM);                         \
  }

#define VMCNT(N) asm volatile("s_waitcnt vmcnt(" #N ")" ::: "memory")
#define LGKM(N)  asm volatile("s_waitcnt lgkmcnt(" #N ")" ::: "memory")
#define SCHED0   __builtin_amdgcn_sched_barrier(0)
#define BAR      __builtin_amdgcn_s_barrier()

#define BREAD(T, KK)                                                         \
  { const char* Bb_ = (const char*)(&Bl[(T) & 1][(KK)][0]);                  \
    bq0 = *(const bf16x8*)(Bb_ + offB[0]);                                   \
    bq1 = *(const bf16x8*)(Bb_ + offB[1]);                                   \
    bq2 = *(const bf16x8*)(Bb_ + offB[2]);                                   \
    bq3 = *(const bf16x8*)(Bb_ + offB[3]); }

#define AREAD(S, T, KK)                                                      \
  { const char* Ab_ = (const char*)(&Al[(T) & 1][(KK)][0]);                  \
    S##0 = *(const bf16x8*)(Ab_ + offA[0]);                                  \
    S##1 = *(const bf16x8*)(Ab_ + offA[1]);                                  \
    S##2 = *(const bf16x8*)(Ab_ + offA[2]);                                  \
    S##3 = *(const bf16x8*)(Ab_ + offA[3]);                                  \
    S##4 = *(const bf16x8*)(Ab_ + offA[4]);                                  \
    S##5 = *(const bf16x8*)(Ab_ + offA[5]);                                  \
    S##6 = *(const bf16x8*)(Ab_ + offA[6]);                                  \
    S##7 = *(const bf16x8*)(Ab_ + offA[7]); }

#define MFMA4(G, I, AF)                                                               \
  acc[(G)*4+(I)][0] = __builtin_amdgcn_mfma_f32_16x16x32_bf16(AF, bq0, acc[(G)*4+(I)][0], 0, 0, 0); \
  acc[(G)*4+(I)][1] = __builtin_amdgcn_mfma_f32_16x16x32_bf16(AF, bq1, acc[(G)*4+(I)][1], 0, 0, 0); \
  acc[(G)*4+(I)][2] = __builtin_amdgcn_mfma_f32_16x16x32_bf16(AF, bq2, acc[(G)*4+(I)][2], 0, 0, 0); \
  acc[(G)*4+(I)][3] = __builtin_amdgcn_mfma_f32_16x16x32_bf16(AF, bq3, acc[(G)*4+(I)][3], 0, 0, 0);

#define MFMA32(S)                                                            \
  __builtin_amdgcn_s_setprio(1);                                             \
  MFMA4(0, 0, S##0) MFMA4(0, 1, S##1) MFMA4(0, 2, S##2) MFMA4(0, 3, S##3)    \
  MFMA4(1, 0, S##4) MFMA4(1, 1, S##5) MFMA4(1, 2, S##6) MFMA4(1, 3, S##7)    \
  __builtin_amdgcn_s_setprio(0);

  // ---- prologue: tile 0 fully + A.k0(1); leave A.k0(1) in flight ----
  STAGE(Al, gA, 0, 0); STAGE(Bl, gB, 0, 0);
  STAGE(Al, gA, 0, 1); STAGE(Bl, gB, 0, 1);
  STAGE(Al, gA, 1, 0);
  VMCNT(2);                      // tile 0 (8 loads) landed; A.k0(1) in flight
  BAR;
  AREAD(s0_, 0, 0);              // set0 <- A.k0(0)   [8 ds_reads outstanding]

  // ---- main loop t = 0..13 (uniform), then peel 14, 15 ----
  for (int t = 0; t < 14; ++t) {
    // phase (t,0): consume set0 (A.k0(t)) x B.k0(t)
    BREAD(t, 0);
    AREAD(s1_, t, 1);            // next phase's A (A.k1(t))
    LGKM(8); SCHED0;             // prev-A + B ready; next-A (8) stays in flight
    MFMA32(s0_);
    STAGE(Bl, gB, t + 1, 0);
    STAGE(Al, gA, t + 1, 1);
    VMCNT(4);                    // covers S(t-1,1) = {A.k0(t+1), B.k1(t)}
    BAR;
    // phase (t,1): consume set1 (A.k1(t)) x B.k1(t)
    BREAD(t, 1);
    AREAD(s0_, t + 1, 0);        // next phase's A (A.k0(t+1))
    LGKM(8); SCHED0;
    MFMA32(s1_);
    STAGE(Al, gA, t + 2, 0);
    STAGE(Bl, gB, t + 1, 1);
    VMCNT(4);                    // covers S(t,0) = {B.k0(t+1), A.k1(t+1)}
    BAR;
  }
  // t = 14
  BREAD(14, 0);
  AREAD(s1_, 14, 1);
  LGKM(8); SCHED0;
  MFMA32(s0_);
  STAGE(Bl, gB, 15, 0);
  STAGE(Al, gA, 15, 1);
  VMCNT(4);                      // covers {A.k0(15), B.k1(14)}
  BAR;
  BREAD(14, 1);
  AREAD(s0_, 15, 0);
  LGKM(8); SCHED0;
  MFMA32(s1_);
  STAGE(Bl, gB, 15, 1);
  VMCNT(2);                      // covers {B.k0(15), A.k1(15)}
  BAR;
  // t = 15
  BREAD(15, 0);
  AREAD(s1_, 15, 1);
  LGKM(8); SCHED0;
  MFMA32(s0_);
  VMCNT(0);                      // drain B.k1(15)
  BAR;
  BREAD(15, 1);
  LGKM(0); SCHED0;               // no next-A issued
  MFMA32(s1_);

  // ---- epilogue: C/D layout col=lane&15, row=(lane>>4)*4+j ----
  int crow = brow + wm * 128 + (lane >> 4) * 4;
  int ccol = bcol + wn * 64 + (lane & 15);
  #pragma unroll
  for (int mi = 0; mi < 8; ++mi)
    #pragma unroll
    for (int n = 0; n < 4; ++n)
      #pragma unroll
      for (int j = 0; j < 4; ++j)
        C[(size_t)(crow + mi * 16 + j) * MDIM + (ccol + n * 16)] = acc[mi][n][j];
}

extern "C" void kernel_launch(void* const* d_in, const int* in_sizes, int n_in,
                              void* d_out, int out_size, void* d_ws, size_t ws_size,
                              hipStream_t stream) {
  const float* x     = (const float*)d_in[0];
  const float* y     = (const float*)d_in[1];
  const float* freqs = (const float*)d_in[2];
  const float* lam   = (const float*)d_in[3];
  const float* var   = (const float*)d_in[4];
  float* out = (float*)d_out;
  float* ws  = (float*)d_ws;

  hipLaunchKernelGGL(scale_kernel, dim3(1), dim3(512), 0, stream, lam, var, ws);
  hipLaunchKernelGGL(phase_kernel, dim3(NDIM + MDIM), dim3(512), 0, stream,
                     x, y, freqs, lam, ws);
  hipLaunchKernelGGL(gemm_kernel, dim3((NDIM / 256) * (MDIM / 256)), dim3(512), 0, stream,
                     out);
}